// Round 16
// baseline (211.705 us; speedup 1.0000x reference)
//
#include <hip/hip_runtime.h>
#include <cmath>

#define NB 16
#define TAILV 3.0f
#define MINV 0.001f
#define CSC 0.984f   // 1 - NB*MINV
#define PSTR 60      // P row stride (f32): 60 mod 32 = 28, gcd 4 -> 8 bank groups

typedef __attribute__((ext_vector_type(8))) _Float16 half8;
typedef __attribute__((ext_vector_type(4))) float f32x4;

#define MFMA16(a,b,c) __builtin_amdgcn_mfma_f32_16x16x32_f16(a,b,c,0,0,0)

__device__ __forceinline__ ushort f2h(float f) {
    union { _Float16 h; ushort u; } v; v.h = (_Float16)f; return v.u;
}
__device__ __forceinline__ float softplus_f(float x) {
    return (x > 20.0f) ? x : __logf(1.0f + __expf(x));   // fast-math: margin absorbs ~ulp error
}

// ---- prologue: convert/transpose weights into d_ws (fp16, [N][K]) ----
// TIGHT W3T layout (1600 rows):
//   rows [0,1536):    n = dim*48 + p   for p<48  (W 0-15 | H 16-31 | D 0-15)
//   rows [1536,1568): n = 1536 + dim   = d16 (17th derivative) per dim
// W2T: [256][256].  W1T: [256][32].  b3p mirrors the W3T n-mapping.
__global__ void __launch_bounds__(256)
cvt_weights(const float* __restrict__ W1, const float* __restrict__ W2,
            const float* __restrict__ W3, const float* __restrict__ b3,
            ushort* __restrict__ W3T, ushort* __restrict__ W2T,
            ushort* __restrict__ W1T, float* __restrict__ b3p)
{
    __shared__ float sm[64][65];
    const int b = blockIdx.x, t = threadIdx.x;
    const int tx = t & 63, ty = t >> 6;

    if (b < 100) {
        const int kt = b / 25, ct = b % 25;
        const int c = ct * 64 + tx;
        #pragma unroll
        for (int i = 0; i < 16; ++i) {
            const int k = kt * 64 + ty * 16 + i;
            float v = (c < 1568) ? W3[(size_t)k * 1568 + c] : 0.0f;
            sm[tx][ty * 16 + i] = v;               // sm[c_local][k_local]
        }
        __syncthreads();
        #pragma unroll
        for (int i = 0; i < 16; ++i) {
            const int clocal = ty * 16 + i;
            const int cc = ct * 64 + clocal;
            if (cc < 1568) {
                const int dim = cc / 49;
                const int p   = cc - dim * 49;
                const int n   = (p < 48) ? (dim * 48 + p) : (1536 + dim);
                W3T[(size_t)n * 256 + kt * 64 + tx] = f2h(sm[clocal][tx]);
            }
        }
    } else if (b < 107) {        // b3p (7 blocks cover n in [0,1792))
        const int n = (b - 100) * 256 + t;
        if (n < 1536) {
            const int dim = n / 48, p = n - dim * 48;
            b3p[n] = b3[dim * 49 + p];
        } else if (n < 1568) {
            b3p[n] = b3[(n - 1536) * 49 + 48];
        } else if (n < 1600) {
            b3p[n] = 0.0f;
        }
    } else if (b < 363) {        // W2T
        const int n = b - 107;
        W2T[(size_t)n * 256 + t] = f2h(W2[(size_t)t * 256 + n]);
    } else {                     // W1T (32 blocks, 8192 elems)
        const int idx = (b - 363) * 256 + t;
        const int n = idx >> 5, k = idx & 31;
        W1T[idx] = f2h(W1[(size_t)k * 256 + n]);
    }
}

// ---- fused main kernel: 64 batch rows / block, 4 waves, 1024 blocks ----
// r16 = r14 verbatim (verified 211.4us total / 149.4us rq_mfma, absmax
// 0.375): tight GEMM3 (-22% B-path work, r13's confirmed lever), P stride
// 60 (gcd-4 bank spread), d16 prologue reusing bnxt. fp8 GEMM3 (r15) is
// REJECTED: tiny-bin sensitivity amplifies ~2% logit noise heavy-tailed
// (z absmax 1.14 > 0.76). This structure's measured plateau: wall = 1.57x
// sum-of-pipes floor, latency-bound at the reg-pinned 2 waves/SIMD.
extern "C" __global__ void __launch_bounds__(256, 2)
rq_mfma(const float* __restrict__ x1, const float* __restrict__ x2,
        const float* __restrict__ b1, const float* __restrict__ b2,
        const ushort* __restrict__ W1T, const ushort* __restrict__ W2T,
        const ushort* __restrict__ W3T, const float* __restrict__ b3p,
        float* __restrict__ zout, float* __restrict__ ldout)
{
    __shared__ char smem[71168];
    float*  sX2  = (float*)smem;                    // [64][33] f32 = 8448
    float*  sLDw = (float*)(smem + 8448);           // [64][5] f32 = 1280
    char*   U    = smem + 9728;                     // 61440-byte union
    ushort* R0   = (ushort*)U;                      // [32][264] fp16 = 16896
    ushort* R1   = (ushort*)(U + 16896);            // [32][264]
    ushort* R2   = (ushort*)(U + 33792);            // [32][264]
    ushort* sA1  = R2;                              // [64][40] fp16 = 5120
    float*  sPw  = (float*)U;                       // 4 waves x [64][60] f32 = 61440

    const int tid  = threadIdx.x;
    const int row0 = blockIdx.x * 64;
    const int rot  = blockIdx.x & 7;
    const int wave = tid >> 6, lane = tid & 63;
    const int ln = lane & 15, kg = lane >> 4;       // frag: m/n=ln, k-group=kg

    // ---- phase 0: stage x1 (->fp16, R2) and x2 (f32) ----
    {
        int r = tid >> 2, c = (tid & 3) << 3;
        float4 v0 = *(const float4*)(x1 + (size_t)(row0 + r) * 32 + c);
        float4 v1 = *(const float4*)(x1 + (size_t)(row0 + r) * 32 + c + 4);
        sA1[r*40 + c    ] = f2h(v0.x); sA1[r*40 + c + 1] = f2h(v0.y);
        sA1[r*40 + c + 2] = f2h(v0.z); sA1[r*40 + c + 3] = f2h(v0.w);
        sA1[r*40 + c + 4] = f2h(v1.x); sA1[r*40 + c + 5] = f2h(v1.y);
        sA1[r*40 + c + 6] = f2h(v1.z); sA1[r*40 + c + 7] = f2h(v1.w);
        float4 w0 = *(const float4*)(x2 + (size_t)(row0 + r) * 32 + c);
        float4 w1 = *(const float4*)(x2 + (size_t)(row0 + r) * 32 + c + 4);
        sX2[r*33 + c    ] = w0.x; sX2[r*33 + c + 1] = w0.y;
        sX2[r*33 + c + 2] = w0.z; sX2[r*33 + c + 3] = w0.w;
        sX2[r*33 + c + 4] = w1.x; sX2[r*33 + c + 5] = w1.y;
        sX2[r*33 + c + 6] = w1.z; sX2[r*33 + c + 7] = w1.w;
    }
    __syncthreads();

    // ---- phase 1: h1 = relu(x1 @ W1 + b1); 4 M-tiles, K=32 ----
    {
        half8 a[4];
        #pragma unroll
        for (int m = 0; m < 4; ++m)
            a[m] = *(const half8*)(sA1 + (m*16 + ln)*40 + kg*8);
        #pragma unroll
        for (int nt = 0; nt < 4; ++nt) {
            int n = wave*64 + nt*16 + ln;
            half8 bfr = *(const half8*)(W1T + n*32 + kg*8);
            float bias = b1[n];
            f32x4 zr = {0.f,0.f,0.f,0.f};
            #pragma unroll
            for (int m = 0; m < 4; ++m) {
                f32x4 cm = MFMA16(a[m], bfr, zr);
                ushort* dst = (m < 2) ? R0 : R1;
                int rb = (m & 1) * 16;
                #pragma unroll
                for (int g = 0; g < 4; ++g)
                    dst[(rb + kg*4 + g)*264 + n] = f2h(fmaxf(cm[g] + bias, 0.f));
            }
        }
    }
    __syncthreads();

    // ---- phase 2: h2 = relu(h1 @ W2 + b2), two 32-row half-passes ----
    #pragma unroll
    for (int part = 0; part < 2; ++part) {
        const ushort* S = (part == 0) ? R0 : R1;   // h1 rows
        ushort*       D = (part == 0) ? R2 : R0;   // h2 rows
        half8 a0[8], a1[8];
        #pragma unroll
        for (int ks = 0; ks < 8; ++ks) {
            a0[ks] = *(const half8*)(S + ln*264 + ks*32 + kg*8);
            a1[ks] = *(const half8*)(S + (16 + ln)*264 + ks*32 + kg*8);
        }
        #pragma unroll
        for (int nt = 0; nt < 4; ++nt) {
            int n = wave*64 + nt*16 + ln;
            f32x4 c0 = {0,0,0,0}, c1 = {0,0,0,0};
            const ushort* bp = W2T + (size_t)n*256 + kg*8;
            #pragma unroll
            for (int ks = 0; ks < 8; ++ks) {
                half8 bfr = *(const half8*)(bp + ks*32);
                c0 = MFMA16(a0[ks], bfr, c0);
                c1 = MFMA16(a1[ks], bfr, c1);
            }
            float bias = b2[n];
            #pragma unroll
            for (int g = 0; g < 4; ++g) {
                D[(kg*4 + g)*264 + n]      = f2h(fmaxf(c0[g] + bias, 0.f));
                D[(16 + kg*4 + g)*264 + n] = f2h(fmaxf(c1[g] + bias, 0.f));
            }
        }
        __syncthreads();
    }

    // ---- phase 3: hoist GEMM3 A-fragments (4 M-tiles x 8 ks = 128 regs) ----
    half8 A[4][8];
    #pragma unroll
    for (int m = 0; m < 4; ++m) {
        const ushort* src = (m < 2) ? R2 : R0;     // h2 rows 0-31 / 32-63
        int rb = (m & 1) * 16;
        #pragma unroll
        for (int ks = 0; ks < 8; ++ks)
            A[m][ks] = *(const half8*)(src + (rb + ln)*264 + ks*32 + kg*8);
    }
    __syncthreads();   // staging dead; sPw overlays U

    // ---- phase 4: GEMM3 + fused spline; wave owns dims [wave*8, wave*8+8) ----
    float* myP = sPw + wave * (64 * PSTR);         // [64][60] f32
    float  ldacc = 0.f;

    half8 bcur[8], bnxt[8];

    // prologue A: d16 tile — 16 cols = d16 of dims [(wave>>1)*16, +16);
    // B-tile staged in bnxt (no separate be[] -> no extra reg pressure);
    // this wave stores the 8 dims it owns into persistent cols 48..55.
    {
        const int ebase = 1536 + (wave >> 1) * 16;
        const ushort* bp = W3T + (size_t)(ebase + ln) * 256 + kg*8;
        #pragma unroll
        for (int ks = 0; ks < 8; ++ks) bnxt[ks] = *(const half8*)(bp + ks*32);
        const float biasE = b3p[ebase + ln];
        f32x4 c[4];
        #pragma unroll
        for (int m = 0; m < 4; ++m) c[m] = (f32x4){0,0,0,0};
        #pragma unroll
        for (int ks = 0; ks < 8; ++ks)
            #pragma unroll
            for (int m = 0; m < 4; ++m)
                c[m] = MFMA16(A[m][ks], bnxt[ks], c[m]);
        if ((ln >> 3) == (wave & 1)) {             // lane's dim owned by this wave
            const int j = ln & 7;
            #pragma unroll
            for (int m = 0; m < 4; ++m)
                #pragma unroll
                for (int g = 0; g < 4; ++g)
                    myP[(m*16 + kg*4 + g)*PSTR + 48 + j] = c[m][g] + biasE;
        }
    }

    // prologue B: first chunk's first B-tile
    {
        int dim0 = wave*8 + rot;
        const ushort* bp = W3T + (size_t)(dim0*48 + ln)*256 + kg*8;
        #pragma unroll
        for (int ks = 0; ks < 8; ++ks) bcur[ks] = *(const half8*)(bp + ks*32);
    }

    for (int ch0 = 0; ch0 < 8; ++ch0) {
        const int dim = wave*8 + ((ch0 + rot) & 7);
        float bias[3];
        #pragma unroll
        for (int nt = 0; nt < 3; ++nt) bias[nt] = b3p[dim*48 + nt*16 + ln];

        #pragma unroll
        for (int nt = 0; nt < 3; ++nt) {
            const bool last = (ch0 == 7) && (nt == 2);
            if (!last) {   // prefetch next tile (rotated order)
                int ndim = (nt == 2) ? (wave*8 + ((ch0 + 1 + rot) & 7)) : dim;
                int nnt  = (nt == 2) ? 0 : nt + 1;
                const ushort* bp = W3T + (size_t)(ndim*48 + nnt*16 + ln)*256 + kg*8;
                #pragma unroll
                for (int ks = 0; ks < 8; ++ks) bnxt[ks] = *(const half8*)(bp + ks*32);
            }
            f32x4 c[4];
            #pragma unroll
            for (int m = 0; m < 4; ++m) c[m] = (f32x4){0,0,0,0};
            #pragma unroll
            for (int ks = 0; ks < 8; ++ks)
                #pragma unroll
                for (int m = 0; m < 4; ++m)
                    c[m] = MFMA16(A[m][ks], bcur[ks], c[m]);
            const int p = nt*16 + ln;              // < 48: every lane real
            #pragma unroll
            for (int m = 0; m < 4; ++m)
                #pragma unroll
                for (int g = 0; g < 4; ++g)
                    myP[(m*16 + kg*4 + g)*PSTR + p] = c[m][g] + bias[nt];
            if (!last) {
                #pragma unroll
                for (int ks = 0; ks < 8; ++ks) bcur[ks] = bnxt[ks];
            }
        }

        // spline: r12-verified body; stride PSTR, d16 col select for d1.
        {
            const float* myPl = myP + lane * PSTR;
            const f32x4* pr   = (const f32x4*)myPl;
            const float x  = sX2[lane*33 + dim];
            const float xc = fminf(fmaxf(x, -TAILV), TAILV);

            f32x4 Lw[4], Lh[4];
            #pragma unroll
            for (int q = 0; q < 4; ++q) Lw[q] = pr[q];       // p 0..15
            #pragma unroll
            for (int q = 0; q < 4; ++q) Lh[q] = pr[4 + q];   // p 16..31

            float e[NB];
            #pragma unroll
            for (int k = 0; k < NB; ++k) e[k] = __expf(Lw[k>>2][k&3]);
            float s;
            {
                float a0=e[0]+e[1],   a1=e[2]+e[3],   a2=e[4]+e[5],   a3=e[6]+e[7];
                float a4=e[8]+e[9],   a5=e[10]+e[11], a6=e[12]+e[13], a7=e[14]+e[15];
                s = ((a0+a1)+(a2+a3)) + ((a4+a5)+(a6+a7));
            }
            const float inv = 1.f / s;

            int idx = 0; float xk = -TAILV, xk1 = TAILV; float cum = 0.f;
            #pragma unroll
            for (int k = 0; k < NB; ++k) {
                float lo = -TAILV + 2.f * TAILV * cum;
                cum += MINV + CSC * e[k] * inv;
                float hi = -TAILV + 2.f * TAILV * cum;
                if (lo <= xc) { idx = k; xk = lo; xk1 = hi; }
            }

            float eh[NB];
            #pragma unroll
            for (int k = 0; k < NB; ++k) eh[k] = __expf(Lh[k>>2][k&3]);
            float sh;
            {
                float a0=eh[0]+eh[1],   a1=eh[2]+eh[3],   a2=eh[4]+eh[5],   a3=eh[6]+eh[7];
                float a4=eh[8]+eh[9],   a5=eh[10]+eh[11], a6=eh[12]+eh[13], a7=eh[14]+eh[15];
                sh = ((a0+a1)+(a2+a3)) + ((a4+a5)+(a6+a7));
            }
            const float invh = 1.f / sh;

            float yk = -TAILV, yk1 = TAILV; cum = 0.f;
            #pragma unroll
            for (int k = 0; k < NB; ++k) {
                float lo = -TAILV + 2.f * TAILV * cum;
                cum += MINV + CSC * eh[k] * invh;
                float hi = -TAILV + 2.f * TAILV * cum;
                if (k == idx) { yk = lo; yk1 = hi; }
            }

            const float d0 = MINV + softplus_f(myPl[32 + idx]);
            const int   i1 = (idx < 15) ? (33 + idx) : (48 + (dim & 7));
            const float d1 = MINV + softplus_f(myPl[i1]);

            const float wd = xk1 - xk, hd = yk1 - yk;
            const float sk = hd / wd;
            const float xi = (xc - xk) / wd;
            const float xim = xi * (1.f - xi);
            const float alpha = hd * (sk * xi * xi + d0 * xim);
            const float beta  = sk + (d1 + d0 - 2.f * sk) * xim;
            const float z     = yk + alpha / beta;
            const float om    = 1.f - xi;
            const float dn    = sk * sk * (d1 * xi * xi + 2.f * sk * xim + d0 * om * om);
            const float ld    = __logf(dn / (beta * beta));

            const bool inside = (x >= -TAILV) && (x <= TAILV);
            zout[(size_t)(row0 + lane) * 32 + dim] = inside ? z : x;
            ldacc += inside ? ld : 0.f;
        }
    }
    sLDw[lane*5 + wave] = ldacc;
    __syncthreads();

    // ---- phase 5: log_det reduction across waves ----
    if (tid < 64) {
        float sld = sLDw[tid*5 + 0] + sLDw[tid*5 + 1]
                  + sLDw[tid*5 + 2] + sLDw[tid*5 + 3];
        ldout[row0 + tid] = sld;
    }
}

extern "C" void kernel_launch(void* const* d_in, const int* in_sizes, int n_in,
                              void* d_out, int out_size, void* d_ws, size_t ws_size,
                              hipStream_t stream)
{
    const float* x1 = (const float*)d_in[0];
    const float* x2 = (const float*)d_in[1];
    const float* W1 = (const float*)d_in[2];
    const float* b1 = (const float*)d_in[3];
    const float* W2 = (const float*)d_in[4];
    const float* b2 = (const float*)d_in[5];
    const float* W3 = (const float*)d_in[6];
    const float* b3 = (const float*)d_in[7];

    // d_ws layout (region offsets kept; W3T uses 1600 of its 2048 rows)
    ushort* W3T = (ushort*)d_ws;                 // 1600*256 fp16 used
    ushort* W2T = W3T + 2048 * 256;              // 256*256 fp16
    ushort* W1T = W2T + 256 * 256;               // 256*32 fp16
    float*  b3p = (float*)(W1T + 256 * 32);      // 1600 f32 used

    float* zout  = (float*)d_out;                // (65536, 32)
    float* ldout = zout + (size_t)65536 * 32;    // (65536,)

    cvt_weights<<<395, 256, 0, stream>>>(W1, W2, W3, b3, W3T, W2T, W1T, b3p);
    rq_mfma<<<1024, 256, 0, stream>>>(x1, x2, b1, b2, W1T, W2T, W3T, b3p, zout, ldout);
}